// Round 6
// baseline (194.727 us; speedup 1.0000x reference)
//
#include <hip/hip_runtime.h>

// Boids ODE segment-sum, counting-sort pipeline v4 (resubmit after infra failure):
//   k_prep  : fused node-record pack + global bucket histogram (LDS hist -> global atomics)
//   k_scanb : single-block exclusive scan of bucket totals -> 4-aligned bases + cursors
//   k_scatter: block-local LDS multisplit, per-bucket global reservation (1 atomic per
//              touched bucket), per-wave segment writes (coalesced runs, no sbkt array)
//   k_accum : per-(bucket,split), 8-way unrolled gather (uint4 pk loads), LDS accumulate

#define BA1 5e-06f
#define BA2 0.0005f
#define BA3 1e-08f

#define NT 256        // threads per block
#define CEPB 4096     // edges per count block
#define SEPB 8192     // edges per scatter block
#define WIN 256       // receiver nodes per bucket
#define WSH 8         // log2(WIN)
#define SPLIT 8       // accum blocks per bucket
#define NBMAX 512     // max buckets

// ---------------- K1: fused pack + count ----------------
__global__ void __launch_bounds__(NT)
k_prep(const float* __restrict__ pos, const float* __restrict__ vel,
       const float* __restrict__ field, const float* __restrict__ p_table,
       const int* __restrict__ ptype, const int* __restrict__ dst,
       int N, int E, int NB, int NCBLK,
       float4* __restrict__ rec4, unsigned* __restrict__ cnt) {
    int bx = blockIdx.x, tid = threadIdx.x;
    if (bx < NCBLK) {
        __shared__ unsigned hist[NBMAX];
        for (int b = tid; b < NBMAX; b += NT) hist[b] = 0u;
        __syncthreads();
        int s = bx * CEPB, e = min(E, s + CEPB);
        int k = s + 4 * tid;
        for (; k + 3 < e; k += 4 * NT) {
            int4 d = *reinterpret_cast<const int4*>(dst + k);
            atomicAdd(&hist[d.x >> WSH], 1u);
            atomicAdd(&hist[d.y >> WSH], 1u);
            atomicAdd(&hist[d.z >> WSH], 1u);
            atomicAdd(&hist[d.w >> WSH], 1u);
        }
        int rem = (e - s) & 3;
        if (tid < rem) atomicAdd(&hist[dst[e - rem + tid] >> WSH], 1u);
        __syncthreads();
        for (int b = tid; b < NB; b += NT)
            if (hist[b]) atomicAdd(&cnt[b], hist[b]);
    } else {
        int i = (bx - NCBLK) * NT + tid;
        if (i >= N) return;
        float2 p = *reinterpret_cast<const float2*>(pos + 2 * i);
        float2 v = *reinterpret_cast<const float2*>(vel + 2 * i);
        int ty = ptype[i];
        rec4[2 * i + 0] = make_float4(p.x, p.y, v.x, v.y);
        rec4[2 * i + 1] = make_float4(field[i],
                                      p_table[3 * ty + 0] * BA1,
                                      p_table[3 * ty + 1] * BA2,
                                      p_table[3 * ty + 2] * BA3);
    }
}

// ---------------- K2: single-block scan of bucket totals ----------------
__global__ void __launch_bounds__(NT)
k_scanb(const unsigned* __restrict__ cnt, unsigned* __restrict__ base,
        unsigned* __restrict__ cursor, int NB) {
    __shared__ unsigned t[NBMAX];
    __shared__ unsigned sz[NBMAX];
    int tid = threadIdx.x;
    for (int i = tid; i < NBMAX; i += NT) {
        unsigned c = (i < NB) ? cnt[i] : 0u;
        sz[i] = (c + 3u) & ~3u;
        t[i] = sz[i];
    }
    __syncthreads();
    for (int o = 1; o < NBMAX; o <<= 1) {
        unsigned v0 = (tid >= o) ? t[tid - o] : 0u;
        unsigned v1 = (tid + NT >= o) ? t[tid + NT - o] : 0u;
        __syncthreads();
        t[tid] += v0;
        t[tid + NT] += v1;
        __syncthreads();
    }
    for (int i = tid; i < NB; i += NT) {
        unsigned b = t[i] - sz[i];
        base[i] = b;
        cursor[i] = b;
    }
}

// ---------------- K3: multisplit scatter with global reservation ----------------
__global__ void __launch_bounds__(NT)
k_scatter(const int* __restrict__ dst, const int* __restrict__ src,
          int E, int NB,
          unsigned* __restrict__ cursor,
          unsigned* __restrict__ pk) {
    __shared__ unsigned lh[NBMAX];     // counts -> inclusive scan
    __shared__ unsigned lofs[NBMAX];   // exclusive local offsets (preserved)
    __shared__ unsigned lcur[NBMAX];   // running cursors -> local ends
    __shared__ unsigned gbase[NBMAX];  // reserved global base per bucket
    __shared__ unsigned sbuf[SEPB];    // locally sorted payloads
    int blk = blockIdx.x, tid = threadIdx.x;
    int s = blk * SEPB, e = min(E, s + SEPB);

    for (int b = tid; b < NBMAX; b += NT) lh[b] = 0u;
    __syncthreads();

    // pass 1: local histogram
    int k = s + 4 * tid;
    for (; k + 3 < e; k += 4 * NT) {
        int4 d = *reinterpret_cast<const int4*>(dst + k);
        atomicAdd(&lh[d.x >> WSH], 1u);
        atomicAdd(&lh[d.y >> WSH], 1u);
        atomicAdd(&lh[d.z >> WSH], 1u);
        atomicAdd(&lh[d.w >> WSH], 1u);
    }
    {
        int rem = (e - s) & 3;
        if (tid < rem) atomicAdd(&lh[dst[e - rem + tid] >> WSH], 1u);
    }
    __syncthreads();
    for (int b = tid; b < NBMAX; b += NT) lofs[b] = lh[b];   // save counts
    __syncthreads();

    // inclusive Hillis-Steele scan (2 elems/thread)
    for (int o = 1; o < NBMAX; o <<= 1) {
        unsigned v0 = (tid >= o) ? lh[tid - o] : 0u;
        unsigned v1 = (tid + NT >= o) ? lh[tid + NT - o] : 0u;
        __syncthreads();
        lh[tid] += v0;
        lh[tid + NT] += v1;
        __syncthreads();
    }
    // exclusive offsets, cursors, and global reservations
    for (int b = tid; b < NBMAX; b += NT) {
        unsigned c = lofs[b];                 // local count
        unsigned ex = lh[b] - c;              // exclusive offset
        lofs[b] = ex;
        lcur[b] = ex;
        if (b < NB && c > 0u) gbase[b] = atomicAdd(&cursor[b], c);
    }
    __syncthreads();

    // pass 2: place payloads into LDS grouped by bucket
    k = s + 4 * tid;
    for (; k + 3 < e; k += 4 * NT) {
        int4 d = *reinterpret_cast<const int4*>(dst + k);
        int4 j = *reinterpret_cast<const int4*>(src + k);
        int b0 = d.x >> WSH; unsigned r0 = atomicAdd(&lcur[b0], 1u);
        sbuf[r0] = ((unsigned)(d.x & (WIN - 1)) << 24) | (unsigned)j.x;
        int b1 = d.y >> WSH; unsigned r1 = atomicAdd(&lcur[b1], 1u);
        sbuf[r1] = ((unsigned)(d.y & (WIN - 1)) << 24) | (unsigned)j.y;
        int b2 = d.z >> WSH; unsigned r2 = atomicAdd(&lcur[b2], 1u);
        sbuf[r2] = ((unsigned)(d.z & (WIN - 1)) << 24) | (unsigned)j.z;
        int b3 = d.w >> WSH; unsigned r3 = atomicAdd(&lcur[b3], 1u);
        sbuf[r3] = ((unsigned)(d.w & (WIN - 1)) << 24) | (unsigned)j.w;
    }
    {
        int rem = (e - s) & 3;
        if (tid < rem) {
            int kk = e - rem + tid;
            int d = dst[kk];
            int b = d >> WSH; unsigned r = atomicAdd(&lcur[b], 1u);
            sbuf[r] = ((unsigned)(d & (WIN - 1)) << 24) | (unsigned)src[kk];
        }
    }
    __syncthreads();

    // write phase: each wave copies whole bucket segments (coalesced runs)
    int wave = tid >> 6, lane = tid & 63;
    const int NW = NT / 64;
    for (int b = wave; b < NB; b += NW) {
        unsigned st = lofs[b], en = lcur[b];
        if (st == en) continue;
        unsigned gb = gbase[b];
        for (unsigned u = st + lane; u < en; u += 64)
            pk[gb + (u - st)] = sbuf[u];
    }
}

// ---------------- K4: per-(bucket,split) accumulate, 8-way unrolled ----------------
__global__ void __launch_bounds__(NT, 4)
k_accum(const float4* __restrict__ rec4,
        const unsigned* __restrict__ pk,
        const unsigned* __restrict__ base,
        const unsigned* __restrict__ cnt,
        int N, int NB,
        float* __restrict__ out) {
    __shared__ float4 wnode[WIN];
    __shared__ float4 wcoef[WIN];
    __shared__ float  acc[2 * WIN];
    int b = blockIdx.x, tid = threadIdx.x;
    int bb = b << WSH;
    int wn = min(N - bb, WIN);

    if (tid < wn) {
        int g = bb + tid;
        wnode[tid] = rec4[2 * g + 0];
        wcoef[tid] = rec4[2 * g + 1];
    }
    acc[tid] = 0.f;
    acc[tid + WIN] = 0.f;
    __syncthreads();

    unsigned s = base[b];
    unsigned c = cnt[b];
    unsigned e = s + c;
    const float* recf = reinterpret_cast<const float*>(rec4);

#define EDGE1(PV)                                                              \
    {                                                                          \
        unsigned p_ = (PV);                                                    \
        int l_ = (int)(p_ >> 24);                                              \
        int j_ = (int)(p_ & 0xFFFFFFu);                                        \
        float4 nj_ = rec4[2 * j_];                                             \
        float  f_  = recf[8 * j_ + 4];                                         \
        float4 w_ = wnode[l_];                                                 \
        float4 c_ = wcoef[l_];                                                 \
        float dpx_ = nj_.x - w_.x, dpy_ = nj_.y - w_.y;                        \
        float dvx_ = nj_.z - w_.z, dvy_ = nj_.w - w_.w;                        \
        float d2_ = dpx_ * dpx_ + dpy_ * dpy_;                                 \
        float sd2_ = (d2_ > 0.f) ? d2_ : 1.f;                                  \
        float cdp_ = c_.y - c_.w / sd2_;                                       \
        float mx_ = (cdp_ * dpx_ + c_.z * dvx_) * f_;                          \
        float my_ = (cdp_ * dpy_ + c_.z * dvy_) * f_;                          \
        atomicAdd(&acc[2 * l_ + 0], mx_);                                      \
        atomicAdd(&acc[2 * l_ + 1], my_);                                      \
    }

    // main: 8 consecutive edges per thread, uint4-aligned pk loads
    unsigned stride = (unsigned)NT * SPLIT * 8u;
    for (unsigned k0 = s + ((unsigned)blockIdx.y * NT + tid) * 8u;
         k0 + 8u <= e; k0 += stride) {
        uint4 a = *reinterpret_cast<const uint4*>(pk + k0);
        uint4 d = *reinterpret_cast<const uint4*>(pk + k0 + 4);
        unsigned pv[8] = {a.x, a.y, a.z, a.w, d.x, d.y, d.z, d.w};
        float4 nj[8];
        float  fj[8];
        int    ll[8];
#pragma unroll
        for (int u = 0; u < 8; ++u) {
            int j_ = (int)(pv[u] & 0xFFFFFFu);
            ll[u] = (int)(pv[u] >> 24);
            nj[u] = rec4[2 * j_];
            fj[u] = recf[8 * j_ + 4];
        }
#pragma unroll
        for (int u = 0; u < 8; ++u) {
            float4 w_ = wnode[ll[u]];
            float4 c_ = wcoef[ll[u]];
            float dpx_ = nj[u].x - w_.x, dpy_ = nj[u].y - w_.y;
            float dvx_ = nj[u].z - w_.z, dvy_ = nj[u].w - w_.w;
            float d2_ = dpx_ * dpx_ + dpy_ * dpy_;
            float sd2_ = (d2_ > 0.f) ? d2_ : 1.f;
            float cdp_ = c_.y - c_.w / sd2_;
            float mx_ = (cdp_ * dpx_ + c_.z * dvx_) * fj[u];
            float my_ = (cdp_ * dpy_ + c_.z * dvy_) * fj[u];
            atomicAdd(&acc[2 * ll[u] + 0], mx_);
            atomicAdd(&acc[2 * ll[u] + 1], my_);
        }
    }
    // tail: last (c & 7) edges
    unsigned tail = c & 7u;
    if (blockIdx.y == 0 && tid < tail) EDGE1(pk[e - tail + tid]);
#undef EDGE1

    __syncthreads();
    for (int t = tid; t < 2 * wn; t += NT)
        atomicAdd(&out[2 * bb + t], acc[t]);
}

// ---------------- fallback: baseline edge-parallel atomics ----------------
__global__ void boids_edge_kernel(const float* __restrict__ pos,
                                  const float* __restrict__ vel,
                                  const float* __restrict__ p_table,
                                  const float* __restrict__ field,
                                  const int* __restrict__ ptype,
                                  const int* __restrict__ dst_idx,
                                  const int* __restrict__ src_idx,
                                  float* __restrict__ out,
                                  int n_edges) {
    int e = blockIdx.x * blockDim.x + threadIdx.x;
    if (e >= n_edges) return;
    int i = dst_idx[e], j = src_idx[e];
    float2 pi = *reinterpret_cast<const float2*>(pos + 2 * i);
    float2 pj = *reinterpret_cast<const float2*>(pos + 2 * j);
    float2 vi = *reinterpret_cast<const float2*>(vel + 2 * i);
    float2 vj = *reinterpret_cast<const float2*>(vel + 2 * j);
    float dpx = pj.x - pi.x, dpy = pj.y - pi.y;
    float dvx = vj.x - vi.x, dvy = vj.y - vi.y;
    int t = ptype[i];
    float p0 = p_table[3 * t + 0], p1 = p_table[3 * t + 1], p2 = p_table[3 * t + 2];
    float d2 = dpx * dpx + dpy * dpy;
    float sd2 = (d2 > 0.0f) ? d2 : 1.0f;
    float cdp = p0 * BA1 - p2 * BA3 / sd2;
    float cdv = p1 * BA2;
    float f = field[j];
    atomicAdd(&out[2 * i + 0], (cdp * dpx + cdv * dvx) * f);
    atomicAdd(&out[2 * i + 1], (cdp * dpy + cdv * dvy) * f);
}

extern "C" void kernel_launch(void* const* d_in, const int* in_sizes, int n_in,
                              void* d_out, int out_size, void* d_ws, size_t ws_size,
                              hipStream_t stream) {
    const float* pos     = (const float*)d_in[0];   // [N,2]
    const float* vel     = (const float*)d_in[1];   // [N,2]
    const float* p_table = (const float*)d_in[2];   // [16,3]
    const float* field   = (const float*)d_in[3];   // [N,1]
    const int*   ptype   = (const int*)d_in[4];     // [N]
    const int*   eidx    = (const int*)d_in[5];     // [2,E]

    int N = in_sizes[0] / 2;
    int E = in_sizes[5] / 2;
    const int* dstI = eidx;
    const int* srcI = eidx + E;
    float* out = (float*)d_out;

    int NB    = (N + WIN - 1) >> WSH;
    int NCBLK = (E + CEPB - 1) / CEPB;
    int NSBLK = (E + SEPB - 1) / SEPB;
    int PBLK  = (N + NT - 1) / NT;

    // ws layout: rec4[2N] | pk[E + 4*NBMAX] | cnt[NB] | base[NB] | cursor[NB]
    size_t off_rec  = 0;
    size_t off_pk   = off_rec + (size_t)N * 2 * sizeof(float4);
    size_t off_cnt  = off_pk + ((size_t)E + 4 * NBMAX) * 4;
    size_t off_base = off_cnt + (size_t)NB * 4;
    size_t off_cur  = off_base + (size_t)NB * 4;
    size_t need     = off_cur + (size_t)NB * 4;

    bool ok = (ws_size >= need) && (NB <= NBMAX) && (N <= (1 << 24)) &&
              ((E & 3) == 0);

    if (!ok) {
        hipMemsetAsync(out, 0, (size_t)out_size * sizeof(float), stream);
        int grid = (E + NT - 1) / NT;
        boids_edge_kernel<<<grid, NT, 0, stream>>>(pos, vel, p_table, field,
                                                   ptype, dstI, srcI, out, E);
        return;
    }

    float4*   rec4   = (float4*)((char*)d_ws + off_rec);
    unsigned* pk     = (unsigned*)((char*)d_ws + off_pk);
    unsigned* cnt    = (unsigned*)((char*)d_ws + off_cnt);
    unsigned* basep  = (unsigned*)((char*)d_ws + off_base);
    unsigned* cursor = (unsigned*)((char*)d_ws + off_cur);

    hipMemsetAsync(out, 0, (size_t)out_size * sizeof(float), stream);
    hipMemsetAsync(cnt, 0, (size_t)NB * 4, stream);

    k_prep   <<<NCBLK + PBLK, NT, 0, stream>>>(pos, vel, field, p_table, ptype,
                                               dstI, N, E, NB, NCBLK, rec4, cnt);
    k_scanb  <<<1, NT, 0, stream>>>(cnt, basep, cursor, NB);
    k_scatter<<<NSBLK, NT, 0, stream>>>(dstI, srcI, E, NB, cursor, pk);
    dim3 agrid(NB, SPLIT);
    k_accum  <<<agrid, NT, 0, stream>>>(rec4, pk, basep, cnt, N, NB, out);
}